// Round 1
// baseline (459.229 us; speedup 1.0000x reference)
//
#include <hip/hip_runtime.h>

#define S 16
// ws layout (floats):
// [0, 122880)        normalized linear weights  [30][256][16]
// [122880, 123136)   normalized last weights    [256]
// [123136, 124160)   leaf table                 [32][2][16]  (bit=1 half, bit=0 half)
#define W_LAST 122880
#define W_LEAF 123136

__global__ __launch_bounds__(64) void prep_weights(const float* __restrict__ sw,
                                                   const float* __restrict__ swl,
                                                   float* __restrict__ ws) {
    int c = blockIdx.x;          // 0..479: (step, oc); 480: last column
    int lane = threadIdx.x;
    float v[4];
    if (c < 480) {
        int step = c >> 4, oc = c & 15;
        const float* src = sw + step * 4096 + oc;
        #pragma unroll
        for (int k = 0; k < 4; ++k) v[k] = src[(lane + 64 * k) * 16];
    } else {
        #pragma unroll
        for (int k = 0; k < 4; ++k) v[k] = swl[lane + 64 * k];
    }
    float m = fmaxf(fmaxf(v[0], v[1]), fmaxf(v[2], v[3]));
    #pragma unroll
    for (int off = 32; off >= 1; off >>= 1) m = fmaxf(m, __shfl_xor(m, off));
    float s = 0.f;
    #pragma unroll
    for (int k = 0; k < 4; ++k) { v[k] = __expf(v[k] - m); s += v[k]; }
    #pragma unroll
    for (int off = 32; off >= 1; off >>= 1) s += __shfl_xor(s, off);
    float inv = 1.0f / s;
    if (c < 480) {
        int step = c >> 4, oc = c & 15;
        float* dst = ws + step * 4096 + oc;
        #pragma unroll
        for (int k = 0; k < 4; ++k) dst[(lane + 64 * k) * 16] = v[k] * inv;
    } else {
        #pragma unroll
        for (int k = 0; k < 4; ++k) ws[W_LAST + lane + 64 * k] = v[k] * inv;
    }
}

__global__ void prep_leaf(const float* __restrict__ ll, float* __restrict__ ws) {
    int i = threadIdx.x;  // v*16 + s
    if (i < 512) {
        float l = ll[i];
        int v = i >> 4, s = i & 15;
        float e = log1pf(__expf(-fabsf(l)));
        float lsp = fminf(l, 0.f) - e;   // log_sigmoid(l)
        float lsn = fminf(-l, 0.f) - e;  // log_sigmoid(-l)
        ws[W_LEAF + v * 32 + s] = lsp;
        ws[W_LEAF + v * 32 + 16 + s] = lsn;
    }
}

__global__ __launch_bounds__(64) void spn_main(const int* __restrict__ x,
                                               const float* __restrict__ ws,
                                               float* __restrict__ out) {
    __shared__ __align__(16) float sW[4096];
    __shared__ __align__(16) float sLeaf[1024];
    __shared__ float sEA[64 * 17];    // per-lane ea scratch, padded stride 17
    const int lane = threadIdx.x;
    const int b = blockIdx.x * 64 + lane;

    for (int k = lane; k < 1024; k += 64) sLeaf[k] = ws[W_LEAF + k];

    unsigned bits = 0;
    const int4* xr = (const int4*)(x + b * 32);
    #pragma unroll
    for (int q = 0; q < 8; ++q) {
        int4 w = xr[q];
        bits |= (unsigned)(w.x & 1) << (q * 4 + 0);
        bits |= (unsigned)(w.y & 1) << (q * 4 + 1);
        bits |= (unsigned)(w.z & 1) << (q * 4 + 2);
        bits |= (unsigned)(w.w & 1) << (q * 4 + 3);
    }
    __syncthreads();

    float a[16];
    {
        const float* lf = sLeaf + ((bits & 1) ? 0 : 16);
        #pragma unroll
        for (int s = 0; s < 16; ++s) a[s] = lf[s];
    }

    for (int c = 0; c < 31; ++c) {
        __syncthreads();                     // all lanes done reading sW
        if (c < 30) {
            const float4* src = (const float4*)(ws + c * 4096);
            float4* dst = (float4*)sW;
            #pragma unroll
            for (int k = 0; k < 16; ++k) dst[lane + 64 * k] = src[lane + 64 * k];
        } else {
            const float4* src = (const float4*)(ws + W_LAST);
            ((float4*)sW)[lane] = src[lane];
        }
        __syncthreads();

        const int var = (c < 30) ? (c + 1) : 31;
        const float* lf = sLeaf + var * 32 + (((bits >> var) & 1) ? 0 : 16);
        float bv[16];
        #pragma unroll
        for (int s = 0; s < 16; ++s) bv[s] = lf[s];

        float am = a[0], bm = bv[0];
        #pragma unroll
        for (int s = 1; s < 16; ++s) { am = fmaxf(am, a[s]); bm = fmaxf(bm, bv[s]); }
        float eb[16];
        #pragma unroll
        for (int s = 0; s < 16; ++s) {
            sEA[lane * 17 + s] = __expf(a[s] - am);
            eb[s] = __expf(bv[s] - bm);
        }

        if (c < 30) {
            float acc[16];
            #pragma unroll
            for (int s = 0; s < 16; ++s) acc[s] = 0.f;
            #pragma unroll 1
            for (int i = 0; i < 16; ++i) {
                float eai = sEA[lane * 17 + i];
                const float4* wr = (const float4*)(sW + i * 256);
                #pragma unroll
                for (int j = 0; j < 16; ++j) {
                    float e = eai * eb[j];
                    float4 w0 = wr[j * 4 + 0], w1 = wr[j * 4 + 1],
                           w2 = wr[j * 4 + 2], w3 = wr[j * 4 + 3];
                    acc[0]  += e * w0.x; acc[1]  += e * w0.y;
                    acc[2]  += e * w0.z; acc[3]  += e * w0.w;
                    acc[4]  += e * w1.x; acc[5]  += e * w1.y;
                    acc[6]  += e * w1.z; acc[7]  += e * w1.w;
                    acc[8]  += e * w2.x; acc[9]  += e * w2.y;
                    acc[10] += e * w2.z; acc[11] += e * w2.w;
                    acc[12] += e * w3.x; acc[13] += e * w3.y;
                    acc[14] += e * w3.z; acc[15] += e * w3.w;
                }
            }
            float ab = am + bm;
            #pragma unroll
            for (int s = 0; s < 16; ++s) a[s] = ab + __logf(acc[s]);
        } else {
            float acc = 0.f;
            #pragma unroll 1
            for (int i = 0; i < 16; ++i) {
                float eai = sEA[lane * 17 + i];
                const float* wr = sW + i * 16;
                #pragma unroll
                for (int j = 0; j < 16; ++j) acc += eai * eb[j] * wr[j];
            }
            out[b] = am + bm + __logf(acc);
        }
    }
}

extern "C" void kernel_launch(void* const* d_in, const int* in_sizes, int n_in,
                              void* d_out, int out_size, void* d_ws, size_t ws_size,
                              hipStream_t stream) {
    const int*   x   = (const int*)d_in[0];
    const float* ll  = (const float*)d_in[1];
    const float* sw  = (const float*)d_in[2];
    const float* swl = (const float*)d_in[3];
    float* out = (float*)d_out;
    float* ws  = (float*)d_ws;

    hipLaunchKernelGGL(prep_weights, dim3(481), dim3(64), 0, stream, sw, swl, ws);
    hipLaunchKernelGGL(prep_leaf,    dim3(1),   dim3(512), 0, stream, ll, ws);
    hipLaunchKernelGGL(spn_main,     dim3(512), dim3(64), 0, stream, x, ws, out);
}

// Round 2
// 40.366 us; speedup vs baseline: 11.3765x; 11.3765x over previous
//
#include <hip/hip_runtime.h>

// ---------------- ws float layout ----------------
#define COLMAX 0        // [30][16] softmax col max
#define COLSUM 480      // [30][16] softmax col sum(exp)
#define LASTMS 960      // [2] last col max,sum
#define BMTAB  964      // [32][2] leaf max
#define EBTAB  1028     // [32][2][16] exp(lp - max)
#define WFOLD  2052     // [30][2][16][16] folded single-step weights
#define WLF    17412    // [2][16] folded last step
#define PTAB   17448    // [15][4][16][20] pair products, transposed [oc][i], padded
// total 36648 floats = 147 KB

__device__ __forceinline__ float logsig(float z) {
    return fminf(z, 0.f) - log1pf(__expf(-fabsf(z)));
}

// softmax column stats over 256 in-channels per (step, oc)
__global__ __launch_bounds__(64) void k1_colstats(const float* __restrict__ sw,
                                                  const float* __restrict__ swl,
                                                  float* __restrict__ ws) {
    int c = blockIdx.x;  // 0..479 = step*16+oc ; 480 = last
    int lane = threadIdx.x;
    float v[4];
    if (c < 480) {
        int step = c >> 4, oc = c & 15;
        const float* src = sw + step * 4096 + oc;
        #pragma unroll
        for (int k = 0; k < 4; ++k) v[k] = src[(lane + 64 * k) * 16];
    } else {
        #pragma unroll
        for (int k = 0; k < 4; ++k) v[k] = swl[lane + 64 * k];
    }
    float m = fmaxf(fmaxf(v[0], v[1]), fmaxf(v[2], v[3]));
    #pragma unroll
    for (int off = 32; off >= 1; off >>= 1) m = fmaxf(m, __shfl_xor(m, off));
    float s = 0.f;
    #pragma unroll
    for (int k = 0; k < 4; ++k) s += __expf(v[k] - m);
    #pragma unroll
    for (int off = 32; off >= 1; off >>= 1) s += __shfl_xor(s, off);
    if (lane == 0) {
        if (c < 480) { ws[COLMAX + c] = m; ws[COLSUM + c] = s; }
        else         { ws[LASTMS] = m; ws[LASTMS + 1] = s; }
    }
}

// leaf tables: bm[v][b], eb[v][b][j]
__global__ void k2_leaf(const float* __restrict__ ll, float* __restrict__ ws) {
    int t = threadIdx.x;  // 64 = 32 vars x 2 bits
    if (t >= 64) return;
    int v = t >> 1, b = t & 1;
    float lp[16];
    float m = -1e30f;
    #pragma unroll
    for (int j = 0; j < 16; ++j) {
        float l = ll[v * 16 + j];
        lp[j] = b ? logsig(l) : logsig(-l);
        m = fmaxf(m, lp[j]);
    }
    ws[BMTAB + v * 2 + b] = m;
    #pragma unroll
    for (int j = 0; j < 16; ++j) ws[EBTAB + v * 32 + b * 16 + j] = __expf(lp[j] - m);
}

// fold eb into normalized weights: Wf[c][b][i][oc] = sum_j eb[c+1][b][j] * softmax(W)[i*16+j][oc]
__global__ __launch_bounds__(256) void k3_fold(const float* __restrict__ sw,
                                               const float* __restrict__ swl,
                                               float* __restrict__ ws) {
    int t = blockIdx.x * 256 + threadIdx.x;
    if (t < 15360) {
        int c = t >> 9, rem = t & 511;
        int b = rem >> 8, i = (rem >> 4) & 15, oc = rem & 15;
        float cm = ws[COLMAX + c * 16 + oc];
        float inv = 1.0f / ws[COLSUM + c * 16 + oc];
        const float* eb = ws + EBTAB + (c + 1) * 32 + b * 16;
        const float* wsrc = sw + c * 4096 + i * 256 + oc;
        float acc = 0.f;
        #pragma unroll
        for (int j = 0; j < 16; ++j)
            acc += eb[j] * __expf(wsrc[j * 16] - cm) * inv;
        ws[WFOLD + ((c * 2 + b) * 16 + i) * 16 + oc] = acc;
    } else if (t < 15392) {
        int idx = t - 15360;
        int b = idx >> 4, i = idx & 15;
        float lm = ws[LASTMS], inv = 1.0f / ws[LASTMS + 1];
        const float* eb = ws + EBTAB + 31 * 32 + b * 16;
        float acc = 0.f;
        #pragma unroll
        for (int j = 0; j < 16; ++j)
            acc += eb[j] * __expf(swl[i * 16 + j] - lm) * inv;
        ws[WLF + b * 16 + i] = acc;
    }
}

// pair products: PT[p][v][oc][i] = M[i][oc], M = Wf[2p][b1] * Wf[2p+1][b2]
__global__ __launch_bounds__(256) void k4_pair(float* __restrict__ ws) {
    int t = blockIdx.x * 256 + threadIdx.x;  // 15360
    int p = t >> 10, rem = t & 1023;
    int v = rem >> 8, oc = (rem >> 4) & 15, i = rem & 15;
    int b1 = v >> 1, b2 = v & 1;
    const float* w1 = ws + WFOLD + (((2 * p) * 2 + b1) * 16 + i) * 16;        // [k]
    const float* w2 = ws + WFOLD + (((2 * p + 1) * 2 + b2) * 16) * 16 + oc;   // [k*16]
    float acc = 0.f;
    #pragma unroll
    for (int k = 0; k < 16; ++k) acc += w1[k] * w2[k * 16];
    ws[PTAB + p * 1280 + v * 320 + oc * 20 + i] = acc;
}

__global__ __launch_bounds__(1024) void spn_main(const int* __restrict__ x,
                                                 const float* __restrict__ ws,
                                                 float* __restrict__ out) {
    __shared__ __align__(16) float sPT[19200];
    __shared__ __align__(16) float sWlf[32];
    __shared__ float sBm[64];
    __shared__ __align__(16) float sEb0[32];
    __shared__ __align__(16) float sAcc[64 * 16];
    const int tid = threadIdx.x;

    for (int k = tid; k < 4800; k += 1024)
        ((float4*)sPT)[k] = ((const float4*)(ws + PTAB))[k];
    if (tid < 32) sWlf[tid] = ws[WLF + tid];
    if (tid < 64) sBm[tid] = ws[BMTAB + tid];
    if (tid >= 64 && tid < 96) sEb0[tid - 64] = ws[EBTAB + tid - 64];

    const int g = tid >> 4;       // group in block (0..63) = element
    const int oc = tid & 15;
    const int b = blockIdx.x * 64 + g;

    // gather x bits via ballot: lane (gw,oc) loads vars (2oc, 2oc+1)
    int2 xv = *(const int2*)(x + b * 32 + 2 * oc);
    unsigned long long m0 = __ballot(xv.x & 1);
    unsigned long long m1 = __ballot(xv.y & 1);
    const int gw = (tid >> 4) & 3;
    const unsigned be = (unsigned)(m0 >> (gw * 16)) & 0xffffu;  // var 2k  -> bit k
    const unsigned bo = (unsigned)(m1 >> (gw * 16)) & 0xffffu;  // var 2k+1-> bit k

    __syncthreads();

    // L = sum of leaf maxima over all 32 vars
    float L = 0.f;
    #pragma unroll
    for (int v = 0; v < 32; ++v) {
        int bit = (v & 1) ? ((bo >> (v >> 1)) & 1) : ((be >> (v >> 1)) & 1);
        L += sBm[v * 2 + bit];
    }

    // init r from var-0 leaf (already normalized, max = 1)
    float r[16];
    {
        const float4* e = (const float4*)(sEb0 + (be & 1) * 16);
        #pragma unroll
        for (int k = 0; k < 4; ++k) {
            float4 t4 = e[k];
            r[4 * k] = t4.x; r[4 * k + 1] = t4.y; r[4 * k + 2] = t4.z; r[4 * k + 3] = t4.w;
        }
    }
    float* myAcc = sAcc + g * 16;

    #pragma unroll 1
    for (int p = 0; p < 15; ++p) {
        int v = (((bo >> p) & 1) << 1) | ((be >> (p + 1)) & 1);
        const float* wcol = sPT + p * 1280 + v * 320 + oc * 20;
        float acc = 0.f;
        #pragma unroll
        for (int k = 0; k < 4; ++k) {
            float4 w = *(const float4*)(wcol + k * 4);
            acc += r[4 * k] * w.x + r[4 * k + 1] * w.y + r[4 * k + 2] * w.z + r[4 * k + 3] * w.w;
        }
        myAcc[oc] = acc;
        __builtin_amdgcn_wave_barrier();   // keep write before gather reads
        float4 a0 = *((const float4*)myAcc);
        float4 a1 = *((const float4*)(myAcc + 4));
        float4 a2 = *((const float4*)(myAcc + 8));
        float4 a3 = *((const float4*)(myAcc + 12));
        float mm = fmaxf(fmaxf(fmaxf(a0.x, a0.y), fmaxf(a0.z, a0.w)),
                         fmaxf(fmaxf(a1.x, a1.y), fmaxf(a1.z, a1.w)));
        mm = fmaxf(mm, fmaxf(fmaxf(fmaxf(a2.x, a2.y), fmaxf(a2.z, a2.w)),
                             fmaxf(fmaxf(a3.x, a3.y), fmaxf(a3.z, a3.w))));
        float inv = __builtin_amdgcn_rcpf(mm);
        r[0] = a0.x * inv; r[1] = a0.y * inv; r[2]  = a0.z * inv; r[3]  = a0.w * inv;
        r[4] = a1.x * inv; r[5] = a1.y * inv; r[6]  = a1.z * inv; r[7]  = a1.w * inv;
        r[8] = a2.x * inv; r[9] = a2.y * inv; r[10] = a2.z * inv; r[11] = a2.w * inv;
        r[12] = a3.x * inv; r[13] = a3.y * inv; r[14] = a3.z * inv; r[15] = a3.w * inv;
        L += __logf(mm);
    }

    // last step: OC=1
    {
        const float* wl = sWlf + ((bo >> 15) & 1) * 16;
        float acc = 0.f;
        #pragma unroll
        for (int k = 0; k < 16; ++k) acc += r[k] * wl[k];
        if (oc == 0) out[b] = L + __logf(acc);
    }
}

extern "C" void kernel_launch(void* const* d_in, const int* in_sizes, int n_in,
                              void* d_out, int out_size, void* d_ws, size_t ws_size,
                              hipStream_t stream) {
    const int*   x   = (const int*)d_in[0];
    const float* ll  = (const float*)d_in[1];
    const float* sw  = (const float*)d_in[2];
    const float* swl = (const float*)d_in[3];
    float* out = (float*)d_out;
    float* ws  = (float*)d_ws;

    hipLaunchKernelGGL(k1_colstats, dim3(481), dim3(64), 0, stream, sw, swl, ws);
    hipLaunchKernelGGL(k2_leaf,     dim3(1),   dim3(64), 0, stream, ll, ws);
    hipLaunchKernelGGL(k3_fold,     dim3(61),  dim3(256), 0, stream, sw, swl, ws);
    hipLaunchKernelGGL(k4_pair,     dim3(60),  dim3(256), 0, stream, ws);
    hipLaunchKernelGGL(spn_main,    dim3(512), dim3(1024), 0, stream, x, ws, out);
}

// Round 3
// 31.958 us; speedup vs baseline: 14.3699x; 1.2631x over previous
//
#include <hip/hip_runtime.h>

using uint = unsigned int;

// ws dword layout
#define DW_HI   5440      // PThi base (PTlo at 0); each array 10*544 dwords
#define DW_WLF  10880     // [2][16] f32
#define DW_BM   10912     // [32][2] f32
#define DW_EB0  10976     // [2][16] f32
#define DW_TOT  11008     // 44032 bytes

template<int K>
__device__ __forceinline__ int roti(int x) {
    return __builtin_amdgcn_update_dpp(0, x, 0x120 | K, 0xF, 0xF, true); // row_ror:K
}
template<int K>
__device__ __forceinline__ float rotf(float x) {
    return __builtin_bit_cast(float, roti<K>(__builtin_bit_cast(int, x)));
}
__device__ __forceinline__ float logsig(float z) {
    return fminf(z, 0.f) - log1pf(__expf(-fabsf(z)));
}
__device__ __forceinline__ uint bfpack(float a, float b) { // RNE pack, a->lo, b->hi
    uint ua = __builtin_bit_cast(uint, a);
    uint ub = __builtin_bit_cast(uint, b);
    ua = (ua + 0x7fffu + ((ua >> 16) & 1u)) >> 16;
    ub = ((ub + 0x7fffu + ((ub >> 16) & 1u)) >> 16) << 16;
    return ua | ub;
}
__device__ __forceinline__ float blo(uint u) { return __builtin_bit_cast(float, u << 16); }
__device__ __forceinline__ float bhi(uint u) { return __builtin_bit_cast(float, u & 0xffff0000u); }

// One prep kernel: blocks 0..9 build triple-product tables, block 10 builds WLF/BM/EB0.
__global__ __launch_bounds__(256) void prep(const float* __restrict__ sw,
                                            const float* __restrict__ swl,
                                            const float* __restrict__ ll,
                                            float* __restrict__ ws) {
    __shared__ float sw3[3 * 4096];
    __shared__ float eb[6 * 16];
    __shared__ float cms[48], css[48];
    __shared__ float Wf[6 * 256];
    __shared__ float T1[4 * 256];
    __shared__ float M[8 * 256];

    const int tid = threadIdx.x;
    const int t = blockIdx.x;
    const int lid = tid & 15;

    // empirically derive the rot16 permutation (same intrinsic as main kernel)
    int s1 = roti<1>(lid) & 15,  s2 = roti<2>(lid) & 15,  s3 = roti<3>(lid) & 15;
    int s4 = roti<4>(lid) & 15,  s5 = roti<5>(lid) & 15,  s6 = roti<6>(lid) & 15;
    int s7 = roti<7>(lid) & 15,  s8 = roti<8>(lid) & 15,  s9 = roti<9>(lid) & 15;
    int s10 = roti<10>(lid) & 15, s11 = roti<11>(lid) & 15, s12 = roti<12>(lid) & 15;
    int s13 = roti<13>(lid) & 15, s14 = roti<14>(lid) & 15, s15 = roti<15>(lid) & 15;

    if (t < 10) {
        // stage 3 steps of sum_weights
        const float4* src = (const float4*)(sw + t * 3 * 4096);
        for (int k = tid; k < 3072; k += 256) ((float4*)sw3)[k] = src[k];

        // leaf eb for vars 3t+1 .. 3t+3, both bits
        if (tid < 6) {
            int cc = tid >> 1, bb = tid & 1;
            int var = 3 * t + 1 + cc;
            float lp[16]; float m = -1e30f;
            #pragma unroll
            for (int j = 0; j < 16; ++j) {
                float l = ll[var * 16 + j];
                lp[j] = bb ? logsig(l) : logsig(-l);
                m = fmaxf(m, lp[j]);
            }
            #pragma unroll
            for (int j = 0; j < 16; ++j) eb[tid * 16 + j] = __expf(lp[j] - m);
        }
        __syncthreads();

        // col stats: 48 (cc,oc) pairs; 16 rows x 16 lanes, each row does 3 pairs
        {
            int row = tid >> 4;
            for (int q = 0; q < 3; ++q) {
                int pair = row * 3 + q;          // 0..47
                int cc = pair >> 4, oc = pair & 15;
                float m = -1e30f;
                for (int u = 0; u < 16; ++u)
                    m = fmaxf(m, sw3[cc * 4096 + (u * 16 + lid) * 16 + oc]);
                m = fmaxf(m, rotf<1>(m)); m = fmaxf(m, rotf<2>(m));
                m = fmaxf(m, rotf<4>(m)); m = fmaxf(m, rotf<8>(m));
                float s = 0.f;
                for (int u = 0; u < 16; ++u)
                    s += __expf(sw3[cc * 4096 + (u * 16 + lid) * 16 + oc] - m);
                s = s + rotf<1>(s); s = s + rotf<2>(s);
                s = s + rotf<4>(s); s = s + rotf<8>(s);
                if (lid == 0) { cms[pair] = m; css[pair] = s; }
            }
        }
        __syncthreads();

        // Wf[cc*2+b][i][oc] = sum_j eb[cc,b][j] * softmaxcol(sw[c])[i*16+j][oc]
        for (int e = tid; e < 1536; e += 256) {
            int cb = e >> 8;
            int cc = cb >> 1;
            int i = (e >> 4) & 15, oc = e & 15;
            float cm = cms[cc * 16 + oc], inv = 1.f / css[cc * 16 + oc];
            float acc = 0.f;
            #pragma unroll
            for (int j = 0; j < 16; ++j)
                acc += eb[cb * 16 + j] * __expf(sw3[cc * 4096 + (i * 16 + j) * 16 + oc] - cm);
            Wf[cb * 256 + i * 16 + oc] = acc * inv;
        }
        __syncthreads();

        // T1[b12][i][l] = sum_k Wf[0,b1][i][k] * Wf[1,b2][k][l]
        for (int e = tid; e < 1024; e += 256) {
            int b12 = e >> 8, i = (e >> 4) & 15, l = e & 15;
            int b1 = b12 & 1, b2 = (b12 >> 1) & 1;
            const float* w1 = Wf + (0 + b1) * 256 + i * 16;
            const float* w2 = Wf + (2 + b2) * 256;
            float acc = 0.f;
            #pragma unroll
            for (int k = 0; k < 16; ++k) acc += w1[k] * w2[k * 16 + l];
            T1[b12 * 256 + i * 16 + l] = acc;
        }
        __syncthreads();

        // M[v][i][oc] = sum_k T1[v&3][i][k] * Wf[2,b3][k][oc],  v = b1 | b2<<1 | b3<<2
        for (int e = tid; e < 2048; e += 256) {
            int v = e >> 8, i = (e >> 4) & 15, oc = e & 15;
            int b12 = v & 3, b3 = v >> 2;
            const float* t1 = T1 + b12 * 256 + i * 16;
            const float* w3 = Wf + (4 + b3) * 256;
            float acc = 0.f;
            #pragma unroll
            for (int k = 0; k < 16; ++k) acc += t1[k] * w3[k * 16 + oc];
            M[v * 256 + i * 16 + oc] = acc;
        }
        __syncthreads();

        // write permuted bf16 table: PT[t][v][oc][k] = M[v][s_k][oc]
        if (tid < 128) {
            int v = tid >> 4, oc = lid;
            const float* m = M + v * 256;
            float x0 = m[oc * 16 + oc]; // s0 = oc
            float x1 = m[s1 * 16 + oc],  x2 = m[s2 * 16 + oc],  x3 = m[s3 * 16 + oc];
            float x4 = m[s4 * 16 + oc],  x5 = m[s5 * 16 + oc],  x6 = m[s6 * 16 + oc];
            float x7 = m[s7 * 16 + oc],  x8 = m[s8 * 16 + oc],  x9 = m[s9 * 16 + oc];
            float x10 = m[s10 * 16 + oc], x11 = m[s11 * 16 + oc], x12 = m[s12 * 16 + oc];
            float x13 = m[s13 * 16 + oc], x14 = m[s14 * 16 + oc], x15 = m[s15 * 16 + oc];
            uint4 lo4, hi4;
            lo4.x = bfpack(x0, x1);  lo4.y = bfpack(x2, x3);
            lo4.z = bfpack(x4, x5);  lo4.w = bfpack(x6, x7);
            hi4.x = bfpack(x8, x9);  hi4.y = bfpack(x10, x11);
            hi4.z = bfpack(x12, x13); hi4.w = bfpack(x14, x15);
            uint* wsu = (uint*)ws;
            int dw = t * 544 + v * 68 + oc * 4;
            *(uint4*)(wsu + dw) = lo4;
            *(uint4*)(wsu + DW_HI + dw) = hi4;
        }
    } else {
        // block 10: WLF, BM, EB0
        if (tid < 64) {
            float v[4];
            #pragma unroll
            for (int k = 0; k < 4; ++k) v[k] = swl[tid + 64 * k];
            float m = fmaxf(fmaxf(v[0], v[1]), fmaxf(v[2], v[3]));
            #pragma unroll
            for (int off = 32; off >= 1; off >>= 1) m = fmaxf(m, __shfl_xor(m, off));
            float s = 0.f;
            #pragma unroll
            for (int k = 0; k < 4; ++k) s += __expf(v[k] - m);
            #pragma unroll
            for (int off = 32; off >= 1; off >>= 1) s += __shfl_xor(s, off);
            if (tid < 32) {
                int bb = tid >> 4, i = tid & 15;
                float lp[16]; float bm_ = -1e30f;
                #pragma unroll
                for (int j = 0; j < 16; ++j) {
                    float l = ll[31 * 16 + j];
                    lp[j] = bb ? logsig(l) : logsig(-l);
                    bm_ = fmaxf(bm_, lp[j]);
                }
                float acc = 0.f;
                #pragma unroll
                for (int j = 0; j < 16; ++j)
                    acc += __expf(lp[j] - bm_) * __expf(swl[i * 16 + j] - m);
                ws[DW_WLF + bb * 16 + i] = acc / s;
            }
        }
        if (tid >= 64 && tid < 128) {
            int u = tid - 64; int var = u >> 1, bb = u & 1;
            float m = -1e30f;
            #pragma unroll
            for (int j = 0; j < 16; ++j) {
                float l = ll[var * 16 + j];
                m = fmaxf(m, bb ? logsig(l) : logsig(-l));
            }
            ws[DW_BM + u] = m;
        }
        if (tid >= 128 && tid < 160) {
            int u = tid - 128; int bb = u >> 4, j = u & 15;
            float m = -1e30f;
            #pragma unroll
            for (int jj = 0; jj < 16; ++jj) {
                float l = ll[jj];
                m = fmaxf(m, bb ? logsig(l) : logsig(-l));
            }
            float l = ll[j];
            float lp = bb ? logsig(l) : logsig(-l);
            ws[DW_EB0 + bb * 16 + j] = __expf(lp - m);
        }
    }
}

__global__ __launch_bounds__(512, 6) void spn_main(const int* __restrict__ x,
                                                   const float* __restrict__ ws,
                                                   float* __restrict__ out) {
    __shared__ __align__(16) float sL[DW_TOT];
    const int tid = threadIdx.x;
    const int g = tid >> 4, oc = tid & 15;
    const int b = blockIdx.x * 32 + g;

    // gather this element's 32 x-bits via ballot (lane oc loads vars 2oc, 2oc+1)
    int2 xv = *(const int2*)(x + b * 32 + 2 * oc);
    unsigned long long m0 = __ballot(xv.x & 1);
    unsigned long long m1 = __ballot(xv.y & 1);
    const int gw = g & 3;
    unsigned be = (unsigned)(m0 >> (gw * 16)) & 0xffffu;
    unsigned bo = (unsigned)(m1 >> (gw * 16)) & 0xffffu;
    unsigned bits = 0;
    #pragma unroll
    for (int k = 0; k < 16; ++k)
        bits |= (((be >> k) & 1u) << (2 * k)) | (((bo >> k) & 1u) << (2 * k + 1));

    for (int k = tid; k < DW_TOT / 4; k += 512)
        ((float4*)sL)[k] = ((const float4*)ws)[k];
    __syncthreads();

    float L = 0.f;
    #pragma unroll
    for (int v = 0; v < 32; ++v)
        L += sL[DW_BM + 2 * v + ((bits >> v) & 1)];

    float acc = sL[DW_EB0 + (bits & 1) * 16 + oc];

    const uint* sPT = (const uint*)sL;
    const int ocd = oc * 4;

    #pragma unroll 1
    for (int p = 0; p < 10; ++p) {
        int v = (bits >> (3 * p + 1)) & 7;
        int dw = p * 544 + v * 68 + ocd;
        uint4 wl4 = *(const uint4*)(sPT + dw);
        uint4 wh4 = *(const uint4*)(sPT + DW_HI + dw);

        float a1 = rotf<1>(acc),  a2 = rotf<2>(acc),  a3 = rotf<3>(acc);
        float a4 = rotf<4>(acc),  a5 = rotf<5>(acc),  a6 = rotf<6>(acc);
        float a7 = rotf<7>(acc),  a8 = rotf<8>(acc),  a9 = rotf<9>(acc);
        float a10 = rotf<10>(acc), a11 = rotf<11>(acc), a12 = rotf<12>(acc);
        float a13 = rotf<13>(acc), a14 = rotf<14>(acc), a15 = rotf<15>(acc);

        float d0 = acc * blo(wl4.x);
        d0 = fmaf(a1, bhi(wl4.x), d0);
        d0 = fmaf(a2, blo(wl4.y), d0);
        d0 = fmaf(a3, bhi(wl4.y), d0);
        d0 = fmaf(a4, blo(wl4.z), d0);
        d0 = fmaf(a5, bhi(wl4.z), d0);
        d0 = fmaf(a6, blo(wl4.w), d0);
        d0 = fmaf(a7, bhi(wl4.w), d0);
        float d1 = a8 * blo(wh4.x);
        d1 = fmaf(a9,  bhi(wh4.x), d1);
        d1 = fmaf(a10, blo(wh4.y), d1);
        d1 = fmaf(a11, bhi(wh4.y), d1);
        d1 = fmaf(a12, blo(wh4.z), d1);
        d1 = fmaf(a13, bhi(wh4.z), d1);
        d1 = fmaf(a14, blo(wh4.w), d1);
        d1 = fmaf(a15, bhi(wh4.w), d1);
        float d = d0 + d1;

        float mm = fmaxf(d, rotf<1>(d));
        mm = fmaxf(mm, rotf<2>(mm));
        mm = fmaxf(mm, rotf<4>(mm));
        mm = fmaxf(mm, rotf<8>(mm));
        acc = d * __builtin_amdgcn_rcpf(mm);
        L += __logf(mm);
    }

    // last step: fold var 31, OC=1
    float wl = sL[DW_WLF + ((bits >> 31) & 1) * 16 + oc];
    float ts = acc * wl;
    ts = ts + rotf<1>(ts);
    ts = ts + rotf<2>(ts);
    ts = ts + rotf<4>(ts);
    ts = ts + rotf<8>(ts);
    if (oc == 0) out[b] = L + __logf(ts);
}

extern "C" void kernel_launch(void* const* d_in, const int* in_sizes, int n_in,
                              void* d_out, int out_size, void* d_ws, size_t ws_size,
                              hipStream_t stream) {
    const int*   x   = (const int*)d_in[0];
    const float* ll  = (const float*)d_in[1];
    const float* sw  = (const float*)d_in[2];
    const float* swl = (const float*)d_in[3];
    float* out = (float*)d_out;
    float* ws  = (float*)d_ws;

    hipLaunchKernelGGL(prep,     dim3(11),   dim3(256), 0, stream, sw, swl, ll, ws);
    hipLaunchKernelGGL(spn_main, dim3(1024), dim3(512), 0, stream, x, ws, out);
}

// Round 4
// 25.761 us; speedup vs baseline: 17.8265x; 1.2405x over previous
//
#include <hip/hip_runtime.h>

using uint = unsigned int;

// ws dword layout
#define DW_LO    0        // [7][16][16][4+] bf16-pairs lo (k0..7), v-stride 68, p-stride 1088
#define DW_HIb   7616     // hi (k8..15)
#define DW_FT    15232    // [8][16] f32 final-triple vectors
#define DW_DELTA 15360    // [32] f32 bm[v][1]-bm[v][0]
#define DW_BASE  15392    // [1]  sum bm[v][0]
#define DW_EB0   15396    // [2][16] f32 normalized var-0 leaf
#define DW_TOT   15616    // padded (3904 float4)

template<int K>
__device__ __forceinline__ int roti(int x) {
    return __builtin_amdgcn_update_dpp(0, x, 0x120 | K, 0xF, 0xF, true); // row_ror:K
}
template<int K>
__device__ __forceinline__ float rotf(float x) {
    return __builtin_bit_cast(float, roti<K>(__builtin_bit_cast(int, x)));
}
__device__ __forceinline__ float logsig(float z) {
    return fminf(z, 0.f) - log1pf(__expf(-fabsf(z)));
}
__device__ __forceinline__ uint bfpack(float a, float b) { // RNE pack, a->lo, b->hi
    uint ua = __builtin_bit_cast(uint, a);
    uint ub = __builtin_bit_cast(uint, b);
    ua = (ua + 0x7fffu + ((ua >> 16) & 1u)) >> 16;
    ub = ((ub + 0x7fffu + ((ub >> 16) & 1u)) >> 16) << 16;
    return ua | ub;
}
__device__ __forceinline__ float blo(uint u) { return __builtin_bit_cast(float, u << 16); }
__device__ __forceinline__ float bhi(uint u) { return __builtin_bit_cast(float, u & 0xffff0000u); }

// 8 blocks x 1024 threads. Blocks 0..6: quad tables (vars 4t+1..4t+4).
// Block 7: final triple (vars 29,30,31 -> OC=1), delta/base, EB0.
__global__ __launch_bounds__(1024) void prep(const float* __restrict__ sw,
                                             const float* __restrict__ swl,
                                             const float* __restrict__ ll,
                                             float* __restrict__ ws) {
    __shared__ __align__(16) float SW[16384];   // 4 steps of raw W -> Sexp in place
    __shared__ float EB[128];                   // [cb][j]
    __shared__ float CM[64], CS[64];
    __shared__ float WF[2048];                  // [cb][i][oc]
    __shared__ float T12[2048];                 // T1 | T2
    __shared__ float MM[4096];                  // [v][i][oc]
    __shared__ float WL[32];
    __shared__ float BMs[64];

    const int tid = threadIdx.x;
    const int t = blockIdx.x;
    const int lid = tid & 15;

    // derive the row_ror permutation empirically (must match main kernel)
    int s1 = roti<1>(lid) & 15,   s2 = roti<2>(lid) & 15,   s3 = roti<3>(lid) & 15;
    int s4 = roti<4>(lid) & 15,   s5 = roti<5>(lid) & 15,   s6 = roti<6>(lid) & 15;
    int s7 = roti<7>(lid) & 15,   s8 = roti<8>(lid) & 15,   s9 = roti<9>(lid) & 15;
    int s10 = roti<10>(lid) & 15, s11 = roti<11>(lid) & 15, s12 = roti<12>(lid) & 15;
    int s13 = roti<13>(lid) & 15, s14 = roti<14>(lid) & 15, s15 = roti<15>(lid) & 15;

    if (t < 7) {
        const float4* src = (const float4*)sw + t * 4096;
        #pragma unroll
        for (int k = 0; k < 4; ++k) ((float4*)SW)[tid + 1024 * k] = src[tid + 1024 * k];
        if (tid < 128) {  // EB: cc=tid>>5, b=(tid>>4)&1, j=lid
            int cc = tid >> 5, bb = (tid >> 4) & 1, var = 4 * t + 1 + cc;
            float l = ll[var * 16 + lid];
            float lp = bb ? logsig(l) : logsig(-l);
            float m = lp;
            m = fmaxf(m, rotf<1>(m)); m = fmaxf(m, rotf<2>(m));
            m = fmaxf(m, rotf<4>(m)); m = fmaxf(m, rotf<8>(m));
            EB[tid] = __expf(lp - m);
        }
        __syncthreads();
        {   // col max per (cc,oc): group=tid>>4, lane j=lid
            int grp = tid >> 4, cc = grp >> 4, ocx = grp & 15;
            float m = -1e30f;
            #pragma unroll
            for (int i = 0; i < 16; ++i)
                m = fmaxf(m, SW[cc * 4096 + i * 256 + lid * 16 + ocx]);
            m = fmaxf(m, rotf<1>(m)); m = fmaxf(m, rotf<2>(m));
            m = fmaxf(m, rotf<4>(m)); m = fmaxf(m, rotf<8>(m));
            if (lid == 0) CM[grp] = m;
        }
        __syncthreads();
        {   // Sexp in place, 16 contiguous per thread
            int base = tid * 16;
            const float* cmp = CM + ((base >> 12) << 4);
            #pragma unroll
            for (int e = 0; e < 16; ++e) SW[base + e] = __expf(SW[base + e] - cmp[e]);
        }
        __syncthreads();
        {   // col sum -> inverse
            int grp = tid >> 4, cc = grp >> 4, ocx = grp & 15;
            float s = 0.f;
            #pragma unroll
            for (int i = 0; i < 16; ++i) s += SW[cc * 4096 + i * 256 + lid * 16 + ocx];
            s += rotf<1>(s); s += rotf<2>(s); s += rotf<4>(s); s += rotf<8>(s);
            if (lid == 0) CS[grp] = 1.0f / s;
        }
        __syncthreads();
        #pragma unroll
        for (int q = 0; q < 2; ++q) {   // WF[cb][i][oc]
            int e = tid + q * 1024;
            int cb = e >> 8, cc = cb >> 1, i = (e >> 4) & 15, ocx = e & 15;
            float a = 0.f;
            #pragma unroll
            for (int j = 0; j < 16; ++j)
                a += EB[cb * 16 + j] * SW[cc * 4096 + i * 256 + j * 16 + ocx];
            WF[e] = a * CS[cc * 16 + ocx];
        }
        __syncthreads();
        {   // T1 = Wf0*Wf1 ; T2 = Wf2*Wf3   (tid = b*256 + i*16 + l)
            int bb = tid >> 8, i = (tid >> 4) & 15, l = lid;
            float a = 0.f, a2 = 0.f;
            #pragma unroll
            for (int k = 0; k < 16; ++k) {
                a  += WF[(bb & 1) * 256 + i * 16 + k]       * WF[(2 + (bb >> 1)) * 256 + k * 16 + l];
                a2 += WF[(4 + (bb & 1)) * 256 + i * 16 + k] * WF[(6 + (bb >> 1)) * 256 + k * 16 + l];
            }
            T12[tid] = a;
            T12[1024 + tid] = a2;
        }
        __syncthreads();
        #pragma unroll
        for (int q = 0; q < 4; ++q) {   // MM[v][i][oc] = T1[v&3] * T2[v>>2]
            int e = tid + q * 1024;
            int v = e >> 8, i = (e >> 4) & 15, ocx = e & 15;
            float a = 0.f;
            #pragma unroll
            for (int k = 0; k < 16; ++k)
                a += T12[(v & 3) * 256 + i * 16 + k] * T12[1024 + (v >> 2) * 256 + k * 16 + ocx];
            MM[e] = a;
        }
        __syncthreads();
        if (tid < 256) {   // permuted bf16 write
            int v = tid >> 4, ocx = lid;
            const float* m = MM + v * 256;
            float x0 = m[ocx * 16 + ocx];
            float x1 = m[s1 * 16 + ocx],   x2 = m[s2 * 16 + ocx],   x3 = m[s3 * 16 + ocx];
            float x4 = m[s4 * 16 + ocx],   x5 = m[s5 * 16 + ocx],   x6 = m[s6 * 16 + ocx];
            float x7 = m[s7 * 16 + ocx],   x8 = m[s8 * 16 + ocx],   x9 = m[s9 * 16 + ocx];
            float x10 = m[s10 * 16 + ocx], x11 = m[s11 * 16 + ocx], x12 = m[s12 * 16 + ocx];
            float x13 = m[s13 * 16 + ocx], x14 = m[s14 * 16 + ocx], x15 = m[s15 * 16 + ocx];
            uint4 lo4, hi4;
            lo4.x = bfpack(x0, x1);   lo4.y = bfpack(x2, x3);
            lo4.z = bfpack(x4, x5);   lo4.w = bfpack(x6, x7);
            hi4.x = bfpack(x8, x9);   hi4.y = bfpack(x10, x11);
            hi4.z = bfpack(x12, x13); hi4.w = bfpack(x14, x15);
            uint* wsu = (uint*)ws;
            int dw = t * 1088 + v * 68 + ocx * 4;
            *(uint4*)(wsu + dw) = lo4;
            *(uint4*)(wsu + DW_HIb + dw) = hi4;
        }
    } else {
        // ---- block 7: final triple + scalars ----
        const float4* s28 = (const float4*)(sw + 28 * 4096);
        #pragma unroll
        for (int k = 0; k < 2; ++k) ((float4*)SW)[tid + 1024 * k] = s28[tid + 1024 * k];
        if (tid < 64) ((float4*)SW)[2048 + tid] = ((const float4*)swl)[tid];
        if (tid < 96) {  // EB: cb 0..3 -> vars 29,30 ; cb 4,5 -> var 31
            int cb = tid >> 4, bb = cb & 1;
            int var = (cb < 4) ? (29 + (cb >> 1)) : 31;
            float l = ll[var * 16 + lid];
            float lp = bb ? logsig(l) : logsig(-l);
            float m = lp;
            m = fmaxf(m, rotf<1>(m)); m = fmaxf(m, rotf<2>(m));
            m = fmaxf(m, rotf<4>(m)); m = fmaxf(m, rotf<8>(m));
            EB[tid] = __expf(lp - m);
        }
        __syncthreads();
        if (tid < 528) {  // col max: 32 (cc,oc) + 1 last-col
            int grp = tid >> 4;
            float m = -1e30f;
            if (grp < 32) {
                int cc = grp >> 4, ocx = grp & 15;
                #pragma unroll
                for (int i = 0; i < 16; ++i)
                    m = fmaxf(m, SW[cc * 4096 + i * 256 + lid * 16 + ocx]);
            } else {
                #pragma unroll
                for (int i = 0; i < 16; ++i)
                    m = fmaxf(m, SW[8192 + i * 16 + lid]);
            }
            m = fmaxf(m, rotf<1>(m)); m = fmaxf(m, rotf<2>(m));
            m = fmaxf(m, rotf<4>(m)); m = fmaxf(m, rotf<8>(m));
            if (lid == 0) CM[grp] = m;
        }
        __syncthreads();
        for (int idx = tid; idx < 8448; idx += 1024) {
            float cm = (idx < 8192) ? CM[((idx >> 12) << 4) | (idx & 15)] : CM[32];
            SW[idx] = __expf(SW[idx] - cm);
        }
        __syncthreads();
        if (tid < 528) {
            int grp = tid >> 4;
            float s = 0.f;
            if (grp < 32) {
                int cc = grp >> 4, ocx = grp & 15;
                #pragma unroll
                for (int i = 0; i < 16; ++i) s += SW[cc * 4096 + i * 256 + lid * 16 + ocx];
            } else {
                #pragma unroll
                for (int i = 0; i < 16; ++i) s += SW[8192 + i * 16 + lid];
            }
            s += rotf<1>(s); s += rotf<2>(s); s += rotf<4>(s); s += rotf<8>(s);
            if (lid == 0) CS[grp] = 1.0f / s;
        }
        __syncthreads();
        {   // WF for c=28,29 (4 x 256)
            int cb = tid >> 8, cc = cb >> 1, i = (tid >> 4) & 15, ocx = lid;
            float a = 0.f;
            #pragma unroll
            for (int j = 0; j < 16; ++j)
                a += EB[cb * 16 + j] * SW[cc * 4096 + i * 256 + j * 16 + ocx];
            WF[tid] = a * CS[cc * 16 + ocx];
        }
        if (tid < 32) {  // WL[b31][i]
            int bb = tid >> 4;
            float a = 0.f;
            #pragma unroll
            for (int j = 0; j < 16; ++j)
                a += EB[(4 + bb) * 16 + j] * SW[8192 + lid * 16 + j];
            WL[tid] = a * CS[32];
        }
        __syncthreads();
        {   // t01[b01][i][l] = Wf28_b0 * Wf29_b1
            int b01 = tid >> 8, i = (tid >> 4) & 15, l = lid;
            float a = 0.f;
            #pragma unroll
            for (int k = 0; k < 16; ++k)
                a += WF[(b01 & 1) * 256 + i * 16 + k] * WF[(2 + (b01 >> 1)) * 256 + k * 16 + l];
            T12[tid] = a;
        }
        __syncthreads();
        if (tid < 128) {  // FT[v][i] = t01[v&3] . WL[v>>2]
            int v = tid >> 4;
            float a = 0.f;
            #pragma unroll
            for (int l = 0; l < 16; ++l)
                a += T12[(v & 3) * 256 + lid * 16 + l] * WL[(v >> 2) * 16 + l];
            ws[DW_FT + v * 16 + lid] = a;
        }
        if (tid >= 128 && tid < 192) {  // BM[v][b]
            int u = tid - 128, var = u >> 1, bb = u & 1;
            float m = -1e30f;
            #pragma unroll
            for (int j = 0; j < 16; ++j) {
                float l = ll[var * 16 + j];
                m = fmaxf(m, bb ? logsig(l) : logsig(-l));
            }
            BMs[u] = m;
        }
        if (tid >= 192 && tid < 224) {  // EB0
            int u = tid - 192, bb = u >> 4, j = u & 15;
            float m = -1e30f;
            #pragma unroll
            for (int jj = 0; jj < 16; ++jj) {
                float l = ll[jj];
                m = fmaxf(m, bb ? logsig(l) : logsig(-l));
            }
            float l = ll[j];
            ws[DW_EB0 + u] = __expf((bb ? logsig(l) : logsig(-l)) - m);
        }
        __syncthreads();
        if (tid < 32) ws[DW_DELTA + tid] = BMs[2 * tid + 1] - BMs[2 * tid];
        if (tid >= 64 && tid < 128) {
            int u = tid - 64;
            float vb = (u < 32) ? BMs[2 * u] : 0.f;
            #pragma unroll
            for (int off = 32; off >= 1; off >>= 1) vb += __shfl_xor(vb, off);
            if (u == 0) ws[DW_BASE] = vb;
        }
    }
}

__global__ __launch_bounds__(512, 4) void spn_main(const int* __restrict__ x,
                                                   const float* __restrict__ ws,
                                                   float* __restrict__ out) {
    __shared__ __align__(16) float sL[DW_TOT];
    const int tid = threadIdx.x;
    const int g = tid >> 4, oc = tid & 15;
    const int b = blockIdx.x * 32 + g;

    int2 xv = *(const int2*)(x + b * 32 + 2 * oc);
    unsigned long long m0 = __ballot(xv.x & 1);
    unsigned long long m1 = __ballot(xv.y & 1);
    const int gw = g & 3;
    unsigned be = (unsigned)(m0 >> (gw * 16)) & 0xffffu;
    unsigned bo = (unsigned)(m1 >> (gw * 16)) & 0xffffu;
    unsigned bits = 0;
    #pragma unroll
    for (int k = 0; k < 16; ++k)
        bits |= (((be >> k) & 1u) << (2 * k)) | (((bo >> k) & 1u) << (2 * k + 1));

    for (int k = tid; k < DW_TOT / 4; k += 512)
        ((float4*)sL)[k] = ((const float4*)ws)[k];
    __syncthreads();

    // L = base + sum_v bit_v * delta_v  (lane oc owns vars 2oc, 2oc+1)
    float2 dl = *(const float2*)(sL + DW_DELTA + 2 * oc);
    float part = 0.f;
    if (xv.x & 1) part += dl.x;
    if (xv.y & 1) part += dl.y;
    part += rotf<1>(part); part += rotf<2>(part);
    part += rotf<4>(part); part += rotf<8>(part);
    float L = sL[DW_BASE] + part;

    float acc = sL[DW_EB0 + (bits & 1) * 16 + oc];
    const uint* sPT = (const uint*)sL;
    const int ocd = oc * 4;

    #pragma unroll
    for (int p = 0; p < 7; ++p) {
        int v = (bits >> (4 * p + 1)) & 15;
        int dw = p * 1088 + v * 68 + ocd;
        uint4 wl4 = *(const uint4*)(sPT + dw);
        uint4 wh4 = *(const uint4*)(sPT + DW_HIb + dw);

        float a1 = rotf<1>(acc),   a2 = rotf<2>(acc),   a3 = rotf<3>(acc);
        float a4 = rotf<4>(acc),   a5 = rotf<5>(acc),   a6 = rotf<6>(acc);
        float a7 = rotf<7>(acc),   a8 = rotf<8>(acc),   a9 = rotf<9>(acc);
        float a10 = rotf<10>(acc), a11 = rotf<11>(acc), a12 = rotf<12>(acc);
        float a13 = rotf<13>(acc), a14 = rotf<14>(acc), a15 = rotf<15>(acc);

        float d0 = acc * blo(wl4.x);
        d0 = fmaf(a1, bhi(wl4.x), d0);
        d0 = fmaf(a2, blo(wl4.y), d0);
        d0 = fmaf(a3, bhi(wl4.y), d0);
        d0 = fmaf(a4, blo(wl4.z), d0);
        d0 = fmaf(a5, bhi(wl4.z), d0);
        d0 = fmaf(a6, blo(wl4.w), d0);
        d0 = fmaf(a7, bhi(wl4.w), d0);
        float d1 = a8 * blo(wh4.x);
        d1 = fmaf(a9,  bhi(wh4.x), d1);
        d1 = fmaf(a10, blo(wh4.y), d1);
        d1 = fmaf(a11, bhi(wh4.y), d1);
        d1 = fmaf(a12, blo(wh4.z), d1);
        d1 = fmaf(a13, bhi(wh4.z), d1);
        d1 = fmaf(a14, blo(wh4.w), d1);
        d1 = fmaf(a15, bhi(wh4.w), d1);
        float d = d0 + d1;

        if (p & 1) {  // normalize every other step (fp32 range is safe for 2 quads)
            float mm = fmaxf(d, rotf<1>(d));
            mm = fmaxf(mm, rotf<2>(mm));
            mm = fmaxf(mm, rotf<4>(mm));
            mm = fmaxf(mm, rotf<8>(mm));
            acc = d * __builtin_amdgcn_rcpf(mm);
            L += __logf(mm);
        } else {
            acc = d;
        }
    }

    // final triple fold (vars 29,30,31 -> OC=1), f32 table
    int v3 = (bits >> 29) & 7;
    float ts = acc * sL[DW_FT + v3 * 16 + oc];
    ts += rotf<1>(ts); ts += rotf<2>(ts);
    ts += rotf<4>(ts); ts += rotf<8>(ts);
    if (oc == 0) out[b] = L + __logf(ts);
}

extern "C" void kernel_launch(void* const* d_in, const int* in_sizes, int n_in,
                              void* d_out, int out_size, void* d_ws, size_t ws_size,
                              hipStream_t stream) {
    const int*   x   = (const int*)d_in[0];
    const float* ll  = (const float*)d_in[1];
    const float* sw  = (const float*)d_in[2];
    const float* swl = (const float*)d_in[3];
    float* out = (float*)d_out;
    float* ws  = (float*)d_ws;

    hipLaunchKernelGGL(prep,     dim3(8),    dim3(1024), 0, stream, sw, swl, ll, ws);
    hipLaunchKernelGGL(spn_main, dim3(1024), dim3(512),  0, stream, x, ws, out);
}

// Round 5
// 23.489 us; speedup vs baseline: 19.5507x; 1.0967x over previous
//
#include <hip/hip_runtime.h>

using uint = unsigned int;

// ws dword layout
#define DW_LO    0        // [7][16v][16oc][4] bf16-pairs lo (k0..7), v-stride 68, p-stride 1088
#define DW_HIb   7616     // hi (k8..15)
#define DW_FT    15232    // [8][16] f32 final-triple vectors
#define DW_DELTA 15360    // [32] f32 bm[v][1]-bm[v][0]
#define DW_BASE  15392    // [1]  sum bm[v][0]
#define DW_EB0   15396    // [2][16] f32 normalized var-0 leaf
#define DW_TOT   15616    // 62.5 KB (3904 float4)

template<int K>
__device__ __forceinline__ int roti(int x) {
    return __builtin_amdgcn_update_dpp(0, x, 0x120 | K, 0xF, 0xF, true); // row_ror:K
}
template<int K>
__device__ __forceinline__ float rotf(float x) {
    return __builtin_bit_cast(float, roti<K>(__builtin_bit_cast(int, x)));
}
__device__ __forceinline__ float rowmax16(float d) {
    d = fmaxf(d, rotf<1>(d)); d = fmaxf(d, rotf<2>(d));
    d = fmaxf(d, rotf<4>(d)); d = fmaxf(d, rotf<8>(d));
    return d;
}
__device__ __forceinline__ float rowsum16(float d) {
    d += rotf<1>(d); d += rotf<2>(d); d += rotf<4>(d); d += rotf<8>(d);
    return d;
}
__device__ __forceinline__ float logsig(float z) {
    return fminf(z, 0.f) - log1pf(__expf(-fabsf(z)));
}
__device__ __forceinline__ uint bfpack(float a, float b) { // RNE pack, a->lo, b->hi
    uint ua = __builtin_bit_cast(uint, a);
    uint ub = __builtin_bit_cast(uint, b);
    ua = (ua + 0x7fffu + ((ua >> 16) & 1u)) >> 16;
    ub = ((ub + 0x7fffu + ((ub >> 16) & 1u)) >> 16) << 16;
    return ua | ub;
}
__device__ __forceinline__ float blo(uint u) { return __builtin_bit_cast(float, u << 16); }
__device__ __forceinline__ float bhi(uint u) { return __builtin_bit_cast(float, u & 0xffff0000u); }
__device__ __forceinline__ unsigned spread16(unsigned u) { // bit k -> bit 2k
    u = (u | (u << 8)) & 0x00FF00FFu;
    u = (u | (u << 4)) & 0x0F0F0F0Fu;
    u = (u | (u << 2)) & 0x33333333u;
    u = (u | (u << 1)) & 0x55555555u;
    return u;
}

// 8 blocks x 1024 threads. Blocks 0..6: quad tables (vars 4t+1..4t+4).
// Block 7: final triple (vars 29,30,31 -> OC=1), delta/base, EB0.
__global__ __launch_bounds__(1024) void prep(const float* __restrict__ sw,
                                             const float* __restrict__ swl,
                                             const float* __restrict__ ll,
                                             float* __restrict__ ws) {
    __shared__ __align__(16) float SW[16384];
    __shared__ float PM[1024];     // col-stat partials [grp][lane]
    __shared__ float EB[128];
    __shared__ float CM[64], CS[64];
    __shared__ float CMl, CSl;     // last-col stats (block 7)
    __shared__ float WF[2048];
    __shared__ float T12[2048];
    __shared__ float MM[4096];
    __shared__ float WL[32];
    __shared__ float BMs[64];

    const int tid = threadIdx.x;
    const int t = blockIdx.x;
    const int lid = tid & 15;

    // derive row_ror permutation empirically (must match main kernel)
    int s1 = roti<1>(lid) & 15,   s2 = roti<2>(lid) & 15,   s3 = roti<3>(lid) & 15;
    int s4 = roti<4>(lid) & 15,   s5 = roti<5>(lid) & 15,   s6 = roti<6>(lid) & 15;
    int s7 = roti<7>(lid) & 15,   s8 = roti<8>(lid) & 15,   s9 = roti<9>(lid) & 15;
    int s10 = roti<10>(lid) & 15, s11 = roti<11>(lid) & 15, s12 = roti<12>(lid) & 15;
    int s13 = roti<13>(lid) & 15, s14 = roti<14>(lid) & 15, s15 = roti<15>(lid) & 15;

    if (t < 7) {
        const float4* src = (const float4*)sw + t * 4096;
        #pragma unroll
        for (int k = 0; k < 4; ++k) ((float4*)SW)[tid + 1024 * k] = src[tid + 1024 * k];
        if (tid < 128) {  // EB
            int cc = tid >> 5, bb = (tid >> 4) & 1, var = 4 * t + 1 + cc;
            float l = ll[var * 16 + lid];
            float lp = bb ? logsig(l) : logsig(-l);
            EB[tid] = __expf(lp - rowmax16(lp));
        }
        __syncthreads();
        {   // col-max partials: grp=(cc,r), lane=oc, contiguous reads
            int grp = tid >> 4, cc = grp >> 4, r = grp & 15;
            float m = -1e30f;
            #pragma unroll
            for (int q = 0; q < 16; ++q)
                m = fmaxf(m, SW[cc * 4096 + (r * 16 + q) * 16 + lid]);
            PM[grp * 16 + lid] = m;
        }
        __syncthreads();
        if (tid < 64) {
            int cc = tid >> 4, ocx = tid & 15;
            float m = -1e30f;
            #pragma unroll
            for (int r = 0; r < 16; ++r) m = fmaxf(m, PM[(cc * 16 + r) * 16 + ocx]);
            CM[tid] = m;
        }
        __syncthreads();
        {   // exp in place (one row of 16 per thread)
            int base = tid * 16;
            const float* cmp = CM + ((tid >> 8) << 4);
            #pragma unroll
            for (int e = 0; e < 16; ++e) SW[base + e] = __expf(SW[base + e] - cmp[e]);
        }
        __syncthreads();
        {   // col-sum partials
            int grp = tid >> 4, cc = grp >> 4, r = grp & 15;
            float s = 0.f;
            #pragma unroll
            for (int q = 0; q < 16; ++q)
                s += SW[cc * 4096 + (r * 16 + q) * 16 + lid];
            PM[grp * 16 + lid] = s;
        }
        __syncthreads();
        if (tid < 64) {
            int cc = tid >> 4, ocx = tid & 15;
            float s = 0.f;
            #pragma unroll
            for (int r = 0; r < 16; ++r) s += PM[(cc * 16 + r) * 16 + ocx];
            CS[tid] = 1.0f / s;
        }
        __syncthreads();
        #pragma unroll
        for (int q = 0; q < 2; ++q) {   // WF[cb][i][oc]
            int e = tid + q * 1024;
            int cb = e >> 8, cc = cb >> 1, i = (e >> 4) & 15, ocx = e & 15;
            float a = 0.f;
            #pragma unroll
            for (int j = 0; j < 16; ++j)
                a += EB[cb * 16 + j] * SW[cc * 4096 + i * 256 + j * 16 + ocx];
            WF[e] = a * CS[cc * 16 + ocx];
        }
        __syncthreads();
        {   // T1 = Wf0*Wf1 ; T2 = Wf2*Wf3
            int bb = tid >> 8, i = (tid >> 4) & 15, l = lid;
            float a = 0.f, a2 = 0.f;
            #pragma unroll
            for (int k = 0; k < 16; ++k) {
                a  += WF[(bb & 1) * 256 + i * 16 + k]       * WF[(2 + (bb >> 1)) * 256 + k * 16 + l];
                a2 += WF[(4 + (bb & 1)) * 256 + i * 16 + k] * WF[(6 + (bb >> 1)) * 256 + k * 16 + l];
            }
            T12[tid] = a;
            T12[1024 + tid] = a2;
        }
        __syncthreads();
        #pragma unroll
        for (int q = 0; q < 4; ++q) {   // MM[v][i][oc]
            int e = tid + q * 1024;
            int v = e >> 8, i = (e >> 4) & 15, ocx = e & 15;
            float a = 0.f;
            #pragma unroll
            for (int k = 0; k < 16; ++k)
                a += T12[(v & 3) * 256 + i * 16 + k] * T12[1024 + (v >> 2) * 256 + k * 16 + ocx];
            MM[e] = a;
        }
        __syncthreads();
        if (tid < 256) {   // permuted bf16 write
            int v = tid >> 4, ocx = lid;
            const float* m = MM + v * 256;
            float x0 = m[ocx * 16 + ocx];
            float x1 = m[s1 * 16 + ocx],   x2 = m[s2 * 16 + ocx],   x3 = m[s3 * 16 + ocx];
            float x4 = m[s4 * 16 + ocx],   x5 = m[s5 * 16 + ocx],   x6 = m[s6 * 16 + ocx];
            float x7 = m[s7 * 16 + ocx],   x8 = m[s8 * 16 + ocx],   x9 = m[s9 * 16 + ocx];
            float x10 = m[s10 * 16 + ocx], x11 = m[s11 * 16 + ocx], x12 = m[s12 * 16 + ocx];
            float x13 = m[s13 * 16 + ocx], x14 = m[s14 * 16 + ocx], x15 = m[s15 * 16 + ocx];
            uint4 lo4, hi4;
            lo4.x = bfpack(x0, x1);   lo4.y = bfpack(x2, x3);
            lo4.z = bfpack(x4, x5);   lo4.w = bfpack(x6, x7);
            hi4.x = bfpack(x8, x9);   hi4.y = bfpack(x10, x11);
            hi4.z = bfpack(x12, x13); hi4.w = bfpack(x14, x15);
            uint* wsu = (uint*)ws;
            int dw = t * 1088 + v * 68 + ocx * 4;
            *(uint4*)(wsu + dw) = lo4;
            *(uint4*)(wsu + DW_HIb + dw) = hi4;
        }
    } else {
        // ---- block 7: final triple + scalars ----
        const float4* s28 = (const float4*)(sw + 28 * 4096);
        #pragma unroll
        for (int k = 0; k < 2; ++k) ((float4*)SW)[tid + 1024 * k] = s28[tid + 1024 * k];
        if (tid < 64) ((float4*)SW)[2048 + tid] = ((const float4*)swl)[tid];
        if (tid < 96) {  // EB: cb 0..3 -> vars 29,30 ; cb 4,5 -> var 31
            int cb = tid >> 4, bb = cb & 1;
            int var = (cb < 4) ? (29 + (cb >> 1)) : 31;
            float l = ll[var * 16 + lid];
            float lp = bb ? logsig(l) : logsig(-l);
            EB[tid] = __expf(lp - rowmax16(lp));
        }
        __syncthreads();
        {   // col-max partials (cc 0..1) + last col
            int grp = tid >> 4;
            if (grp < 32) {
                int cc = grp >> 4, r = grp & 15;
                float m = -1e30f;
                #pragma unroll
                for (int q = 0; q < 16; ++q)
                    m = fmaxf(m, SW[cc * 4096 + (r * 16 + q) * 16 + lid]);
                PM[grp * 16 + lid] = m;
            } else if (grp == 32) {
                float m = -1e30f;
                #pragma unroll
                for (int q = 0; q < 16; ++q) m = fmaxf(m, SW[8192 + q * 16 + lid]);
                m = rowmax16(m);
                if (lid == 0) CMl = m;
            }
        }
        __syncthreads();
        if (tid < 32) {
            int cc = tid >> 4, ocx = tid & 15;
            float m = -1e30f;
            #pragma unroll
            for (int r = 0; r < 16; ++r) m = fmaxf(m, PM[(cc * 16 + r) * 16 + ocx]);
            CM[tid] = m;
        }
        __syncthreads();
        for (int idx = tid; idx < 8448; idx += 1024) {
            float cm = (idx < 8192) ? CM[((idx >> 12) << 4) | (idx & 15)] : CMl;
            SW[idx] = __expf(SW[idx] - cm);
        }
        __syncthreads();
        {
            int grp = tid >> 4;
            if (grp < 32) {
                int cc = grp >> 4, r = grp & 15;
                float s = 0.f;
                #pragma unroll
                for (int q = 0; q < 16; ++q)
                    s += SW[cc * 4096 + (r * 16 + q) * 16 + lid];
                PM[grp * 16 + lid] = s;
            } else if (grp == 32) {
                float s = 0.f;
                #pragma unroll
                for (int q = 0; q < 16; ++q) s += SW[8192 + q * 16 + lid];
                s = rowsum16(s);
                if (lid == 0) CSl = 1.0f / s;
            }
        }
        __syncthreads();
        if (tid < 32) {
            int cc = tid >> 4, ocx = tid & 15;
            float s = 0.f;
            #pragma unroll
            for (int r = 0; r < 16; ++r) s += PM[(cc * 16 + r) * 16 + ocx];
            CS[tid] = 1.0f / s;
        }
        __syncthreads();
        {   // WF for c=28,29
            int cb = tid >> 8, cc = cb >> 1, i = (tid >> 4) & 15, ocx = lid;
            float a = 0.f;
            #pragma unroll
            for (int j = 0; j < 16; ++j)
                a += EB[cb * 16 + j] * SW[cc * 4096 + i * 256 + j * 16 + ocx];
            WF[tid] = a * CS[cc * 16 + ocx];
        }
        if (tid < 32) {  // WL[b31][i]
            int bb = tid >> 4;
            float a = 0.f;
            #pragma unroll
            for (int j = 0; j < 16; ++j)
                a += EB[(4 + bb) * 16 + j] * SW[8192 + lid * 16 + j];
            WL[tid] = a * CSl;
        }
        __syncthreads();
        {   // t01
            int b01 = tid >> 8, i = (tid >> 4) & 15, l = lid;
            float a = 0.f;
            #pragma unroll
            for (int k = 0; k < 16; ++k)
                a += WF[(b01 & 1) * 256 + i * 16 + k] * WF[(2 + (b01 >> 1)) * 256 + k * 16 + l];
            T12[tid] = a;
        }
        __syncthreads();
        if (tid < 128) {  // FT[v][i]
            int v = tid >> 4;
            float a = 0.f;
            #pragma unroll
            for (int l = 0; l < 16; ++l)
                a += T12[(v & 3) * 256 + lid * 16 + l] * WL[(v >> 2) * 16 + l];
            ws[DW_FT + v * 16 + lid] = a;
        }
        if (tid >= 128 && tid < 192) {  // BM[v][b]
            int u = tid - 128, var = u >> 1, bb = u & 1;
            float m = -1e30f;
            #pragma unroll
            for (int j = 0; j < 16; ++j) {
                float l = ll[var * 16 + j];
                m = fmaxf(m, bb ? logsig(l) : logsig(-l));
            }
            BMs[u] = m;
        }
        if (tid >= 192 && tid < 224) {  // EB0
            int u = tid - 192, bb = u >> 4, j = u & 15;
            float m = -1e30f;
            #pragma unroll
            for (int jj = 0; jj < 16; ++jj) {
                float l = ll[jj];
                m = fmaxf(m, bb ? logsig(l) : logsig(-l));
            }
            float l = ll[j];
            ws[DW_EB0 + u] = __expf((bb ? logsig(l) : logsig(-l)) - m);
        }
        __syncthreads();
        if (tid < 32) ws[DW_DELTA + tid] = BMs[2 * tid + 1] - BMs[2 * tid];
        if (tid >= 64 && tid < 128) {
            int u = tid - 64;
            float vb = (u < 32) ? BMs[2 * u] : 0.f;
            #pragma unroll
            for (int off = 32; off >= 1; off >>= 1) vb += __shfl_xor(vb, off);
            if (u == 0) ws[DW_BASE] = vb;
        }
    }
}

__device__ __forceinline__ float quadstep(const uint* sPT, float acc, int dw) {
    uint4 wl4 = *(const uint4*)(sPT + dw);
    uint4 wh4 = *(const uint4*)(sPT + DW_HIb + dw);
    float d0 = acc * blo(wl4.x);
    d0 = fmaf(rotf<1>(acc), bhi(wl4.x), d0);
    d0 = fmaf(rotf<2>(acc), blo(wl4.y), d0);
    d0 = fmaf(rotf<3>(acc), bhi(wl4.y), d0);
    d0 = fmaf(rotf<4>(acc), blo(wl4.z), d0);
    d0 = fmaf(rotf<5>(acc), bhi(wl4.z), d0);
    d0 = fmaf(rotf<6>(acc), blo(wl4.w), d0);
    d0 = fmaf(rotf<7>(acc), bhi(wl4.w), d0);
    float d1 = rotf<8>(acc) * blo(wh4.x);
    d1 = fmaf(rotf<9>(acc),  bhi(wh4.x), d1);
    d1 = fmaf(rotf<10>(acc), blo(wh4.y), d1);
    d1 = fmaf(rotf<11>(acc), bhi(wh4.y), d1);
    d1 = fmaf(rotf<12>(acc), blo(wh4.z), d1);
    d1 = fmaf(rotf<13>(acc), bhi(wh4.z), d1);
    d1 = fmaf(rotf<14>(acc), blo(wh4.w), d1);
    d1 = fmaf(rotf<15>(acc), bhi(wh4.w), d1);
    return d0 + d1;
}

// 512 blocks x 512 threads; each 16-lane group handles elements b0 and b0+32.
__global__ __launch_bounds__(512, 4) void spn_main(const int* __restrict__ x,
                                                   const float* __restrict__ ws,
                                                   float* __restrict__ out) {
    __shared__ __align__(16) float sL[DW_TOT];
    const int tid = threadIdx.x;
    const int g = tid >> 4, oc = tid & 15;
    const int b0 = blockIdx.x * 64 + g;
    const int b1 = b0 + 32;

    int2 xa = *(const int2*)(x + b0 * 32 + 2 * oc);
    int2 xb = *(const int2*)(x + b1 * 32 + 2 * oc);
    unsigned long long ma0 = __ballot(xa.x & 1);
    unsigned long long ma1 = __ballot(xa.y & 1);
    unsigned long long mb0 = __ballot(xb.x & 1);
    unsigned long long mb1 = __ballot(xb.y & 1);
    const int gw = g & 3;
    unsigned bitsA = spread16((unsigned)(ma0 >> (gw * 16)) & 0xffffu)
                   | (spread16((unsigned)(ma1 >> (gw * 16)) & 0xffffu) << 1);
    unsigned bitsB = spread16((unsigned)(mb0 >> (gw * 16)) & 0xffffu)
                   | (spread16((unsigned)(mb1 >> (gw * 16)) & 0xffffu) << 1);

    for (int k = tid; k < DW_TOT / 4; k += 512)
        ((float4*)sL)[k] = ((const float4*)ws)[k];
    __syncthreads();

    // L = base + sum_v bit_v * delta_v (lane oc owns vars 2oc, 2oc+1)
    float2 dl = *(const float2*)(sL + DW_DELTA + 2 * oc);
    float pa = ((xa.x & 1) ? dl.x : 0.f) + ((xa.y & 1) ? dl.y : 0.f);
    float pb = ((xb.x & 1) ? dl.x : 0.f) + ((xb.y & 1) ? dl.y : 0.f);
    float base = sL[DW_BASE];
    float LA = base + rowsum16(pa);
    float LB = base + rowsum16(pb);

    float accA = sL[DW_EB0 + (bitsA & 1) * 16 + oc];
    float accB = sL[DW_EB0 + (bitsB & 1) * 16 + oc];
    const uint* sPT = (const uint*)sL;
    const int ocd = oc * 4;

    #pragma unroll
    for (int p = 0; p < 7; ++p) {
        int dwA = p * 1088 + (int)((bitsA >> (4 * p + 1)) & 15) * 68 + ocd;
        int dwB = p * 1088 + (int)((bitsB >> (4 * p + 1)) & 15) * 68 + ocd;
        float dA = quadstep(sPT, accA, dwA);
        float dB = quadstep(sPT, accB, dwB);
        if (p & 1) {  // normalize every other step
            float mA = rowmax16(dA), mB = rowmax16(dB);
            accA = dA * __builtin_amdgcn_rcpf(mA);
            accB = dB * __builtin_amdgcn_rcpf(mB);
            LA += __logf(mA);
            LB += __logf(mB);
        } else {
            accA = dA; accB = dB;
        }
    }

    // final triple fold (vars 29,30,31 -> OC=1)
    float tsA = rowsum16(accA * sL[DW_FT + ((bitsA >> 29) & 7) * 16 + oc]);
    float tsB = rowsum16(accB * sL[DW_FT + ((bitsB >> 29) & 7) * 16 + oc]);
    if (oc == 0) {
        out[b0] = LA + __logf(tsA);
        out[b1] = LB + __logf(tsB);
    }
}

extern "C" void kernel_launch(void* const* d_in, const int* in_sizes, int n_in,
                              void* d_out, int out_size, void* d_ws, size_t ws_size,
                              hipStream_t stream) {
    const int*   x   = (const int*)d_in[0];
    const float* ll  = (const float*)d_in[1];
    const float* sw  = (const float*)d_in[2];
    const float* swl = (const float*)d_in[3];
    float* out = (float*)d_out;
    float* ws  = (float*)d_ws;

    hipLaunchKernelGGL(prep,     dim3(8),   dim3(1024), 0, stream, sw, swl, ll, ws);
    hipLaunchKernelGGL(spn_main, dim3(512), dim3(512),  0, stream, x, ws, out);
}